// Round 11
// baseline (93.696 us; speedup 1.0000x reference)
//
#include <hip/hip_runtime.h>

typedef short bf16x8 __attribute__((ext_vector_type(8)));
typedef float f32x16 __attribute__((ext_vector_type(16)));

// round-to-nearest-even fp32 -> bf16 (bits)
static __device__ __forceinline__ unsigned short f2bf(float x) {
    unsigned u = __builtin_bit_cast(unsigned, x);
    unsigned r = (u + 0x7FFFu + ((u >> 16) & 1u)) >> 16;
    return (unsigned short)r;
}
static __device__ __forceinline__ float bf2f(unsigned short h) {
    unsigned u = (unsigned)h << 16;
    return __builtin_bit_cast(float, u);
}

// Workspace (shorts): A1[P*16] | A2[P*16] | B1[P*16] | B2[P*16]

// Kernel 1: per point p build MFMA K-vectors (bf16, hi/lo split) for two grams:
//   gram1: denom = 1 + s_i + s_j - 2<c_i,c_j>;  gram2: dot = <n_i,n_j>
// 32x32x16 fragment layout (verified R5-R10, absmax 0.0): point p -> tile=p>>5,
// m=p&31; k0..7 chunk -> lane m, k8..15 -> lane 32+m.
// Targets carry NEGATED normals (folds e_ss - 2 e_st + e_tt into one sum).
__global__ void dc_pack(const float* __restrict__ verts,
                        const float* __restrict__ tnorm,
                        const float* __restrict__ tcent,
                        const int* __restrict__ idx,
                        unsigned short* __restrict__ ws,
                        float* __restrict__ out,
                        int N, int M) {
    int p = blockIdx.x * blockDim.x + threadIdx.x;
    if (p == 0) out[0] = 0.0f;
    int P = N + M;
    if (p >= P) return;

    float cx, cy, cz, nx, ny, nz;
    if (p < N) {
        int i0 = idx[3 * p + 0], i1 = idx[3 * p + 1], i2 = idx[3 * p + 2];
        float ax = verts[3 * i0], ay = verts[3 * i0 + 1], az = verts[3 * i0 + 2];
        float bx = verts[3 * i1], by = verts[3 * i1 + 1], bz = verts[3 * i1 + 2];
        float qx = verts[3 * i2], qy = verts[3 * i2 + 1], qz = verts[3 * i2 + 2];
        float ux = ax - bx, uy = ay - by, uz = az - bz;
        float vx = qx - bx, vy = qy - by, vz = qz - bz;
        nx = 0.5f * (uy * vz - uz * vy);
        ny = 0.5f * (uz * vx - ux * vz);
        nz = 0.5f * (ux * vy - uy * vx);
        cx = (ax + bx + qx) * (1.0f / 3.0f);
        cy = (ay + by + qy) * (1.0f / 3.0f);
        cz = (az + bz + qz) * (1.0f / 3.0f);
    } else {
        int t = p - N;
        cx = tcent[3 * t]; cy = tcent[3 * t + 1]; cz = tcent[3 * t + 2];
        nx = -tnorm[3 * t]; ny = -tnorm[3 * t + 1]; nz = -tnorm[3 * t + 2];
    }

    unsigned short chx = f2bf(cx), chy = f2bf(cy), chz = f2bf(cz);
    unsigned short clx = f2bf(cx - bf2f(chx));
    unsigned short cly = f2bf(cy - bf2f(chy));
    unsigned short clz = f2bf(cz - bf2f(chz));
    unsigned short nhx = f2bf(nx), nhy = f2bf(ny), nhz = f2bf(nz);
    unsigned short nlx = f2bf(nx - bf2f(nhx));
    unsigned short nly = f2bf(ny - bf2f(nhy));
    unsigned short nlz = f2bf(nz - bf2f(nhz));
    float ex = bf2f(chx) + bf2f(clx);
    float ey = bf2f(chy) + bf2f(cly);
    float ez = bf2f(chz) + bf2f(clz);
    float s = ex * ex + ey * ey + ez * ez;
    unsigned short sh = f2bf(s), sl = f2bf(s - bf2f(sh));
    unsigned short m2hx = f2bf(-2.0f * bf2f(chx)), m2hy = f2bf(-2.0f * bf2f(chy)), m2hz = f2bf(-2.0f * bf2f(chz));
    unsigned short m2lx = f2bf(-2.0f * bf2f(clx)), m2ly = f2bf(-2.0f * bf2f(cly)), m2lz = f2bf(-2.0f * bf2f(clz));
    const unsigned short one = 0x3F80;

    __align__(16) unsigned short A1v[16] = {
        m2hx, m2hy, m2hz,  m2hx, m2hy, m2hz,  m2lx, m2ly, m2lz,
        sh, sl,  one, one,  one,  0, 0 };
    __align__(16) unsigned short B1v[16] = {
        chx, chy, chz,  clx, cly, clz,  chx, chy, chz,
        one, one,  sh, sl,  one,  0, 0 };
    __align__(16) unsigned short A2v[16] = {
        nhx, nhy, nhz,  nhx, nhy, nhz,  nlx, nly, nlz,
        0, 0, 0, 0, 0, 0, 0 };
    __align__(16) unsigned short B2v[16] = {
        nhx, nhy, nhz,  nlx, nly, nlz,  nhx, nhy, nhz,
        0, 0, 0, 0, 0, 0, 0 };

    size_t arr = (size_t)P * 16;
    unsigned short* A1 = ws;
    unsigned short* A2 = ws + arr;
    unsigned short* B1 = ws + 2 * arr;
    unsigned short* B2 = ws + 3 * arr;

    int tile = p >> 5, m = p & 31;
    size_t lo = ((size_t)tile * 64 + m) * 8;       // k0..7 -> lane m
    size_t hi = lo + 32 * 8;                       // k8..15 -> lane 32+m

    *(uint4*)(A1 + lo) = *(const uint4*)&A1v[0];
    *(uint4*)(A1 + hi) = *(const uint4*)&A1v[8];
    *(uint4*)(A2 + lo) = *(const uint4*)&A2v[0];
    *(uint4*)(A2 + hi) = *(const uint4*)&A2v[8];
    *(uint4*)(B1 + lo) = *(const uint4*)&B1v[0];
    *(uint4*)(B1 + hi) = *(const uint4*)&B1v[8];
    *(uint4*)(B2 + lo) = *(const uint4*)&B2v[0];
    *(uint4*)(B2 + hi) = *(const uint4*)&B2v[8];
}

// 4-way batched reciprocal: sum of 4 x/a terms via 1 rcp (trans-pipe 4x cut).
static __device__ __forceinline__ void acc4(float4& part, const f32x16& d1, const f32x16& d2) {
#pragma unroll
    for (int g = 0; g < 4; ++g) {
        const int r = 4 * g;
        float p01 = d1[r] * d1[r + 1];
        float p23 = d1[r + 2] * d1[r + 3];
        float n01 = fmaf(d2[r], d1[r + 1], d2[r + 1] * d1[r]);
        float n23 = fmaf(d2[r + 2], d1[r + 3], d2[r + 3] * d1[r + 2]);
        float t   = p01 * p23;
        float num = fmaf(n01, p23, n23 * p01);
        (&part.x)[g] = fmaf(num, __builtin_amdgcn_rcpf(t), (&part.x)[g]);
    }
}

// Kernel 2: row-paired circular symmetric sweep at 6 waves/SIMD.
// Rows (I0=2rp, I1=I0+1) share j-window W=[I0+1, I0+256] (mod nT). Exact:
//   contrib(rp) = 2*sum_W [T(I0,j)+T(I1,j)]
//               + T(I0,I0) + T(I1,I0+257) - T(I0,I0+256) - T(I1,I0+1)
// R5-R10 ran 4-5 waves/SIMD (measured occupancy ~29%) and every intra-wave
// restructuring was neutral -> latency-bound from thin TLP. This round: the
// window is split into 24 chunks (16x11 + 8x10 tiles); 256 rp x 24 = 6144
// waves = 1536 blocks = 6 blocks/CU, still one uniform batch. Gram pairs are
// sequenced d->acc4->e->acc4 to cap VGPR liveness under the (256,6) budget.
__global__ __launch_bounds__(256, 6) void dc_pair_mfma(
    const unsigned short* __restrict__ ws, float* __restrict__ out, int P) {
    __shared__ float wsum[4];

    const int nT = P >> 5;                     // 512
    size_t arr = (size_t)P * 16;
    const unsigned short* A1 = ws;
    const unsigned short* A2 = ws + arr;
    const unsigned short* B1 = ws + 2 * arr;
    const unsigned short* B2 = ws + 3 * arr;

    int tid = threadIdx.x;
    int lane = tid & 63, wv = tid >> 6;
    int gi = blockIdx.x * 4 + wv;              // 0..6143
    int rp = gi / 24, c = gi - 24 * rp;
    int I0 = 2 * rp, I1 = I0 + 1;

    // chunk map over window offsets [1,256]: c<16 -> 11 tiles, else 10
    int st  = (c < 16) ? (1 + 11 * c) : (177 + 10 * (c - 16));
    int len = (c < 16) ? 11 : 10;

    const size_t lo = (size_t)lane * 8;

    bf16x8 a1_0 = *(const bf16x8*)(A1 + (size_t)I0 * 512 + lo);
    bf16x8 a2_0 = *(const bf16x8*)(A2 + (size_t)I0 * 512 + lo);
    bf16x8 a1_1 = *(const bf16x8*)(A1 + (size_t)I1 * 512 + lo);
    bf16x8 a2_1 = *(const bf16x8*)(A2 + (size_t)I1 * 512 + lo);

    const f32x16 zero = {0.f,0.f,0.f,0.f,0.f,0.f,0.f,0.f,0.f,0.f,0.f,0.f,0.f,0.f,0.f,0.f};
    float4 partA = make_float4(0.f, 0.f, 0.f, 0.f);
    float4 corrP = make_float4(0.f, 0.f, 0.f, 0.f);
    float4 corrM = make_float4(0.f, 0.f, 0.f, 0.f);

    auto wrap = [&](int j) -> size_t {
        return (size_t)(j >= nT ? j - nT : j) * 512;   // wave-uniform SALU
    };
    auto one_tile = [&](float4& part, const bf16x8& x1, const bf16x8& x2, int jm) {
        const bf16x8 b1 = *(const bf16x8*)(B1 + (size_t)jm * 512 + lo);
        const bf16x8 b2 = *(const bf16x8*)(B2 + (size_t)jm * 512 + lo);
        f32x16 d1 = __builtin_amdgcn_mfma_f32_32x32x16_bf16(x1, b1, zero, 0, 0, 0);
        f32x16 d2 = __builtin_amdgcn_mfma_f32_32x32x16_bf16(x2, b2, zero, 0, 0, 0);
        acc4(part, d1, d2);
    };

    int js = I0 + st;
#pragma unroll 1
    for (int it = 0; it < len; ++it) {
        size_t o = wrap(js + it);
        bf16x8 b1 = *(const bf16x8*)(B1 + o + lo);
        bf16x8 b2 = *(const bf16x8*)(B2 + o + lo);
        // gram pair for row I0, then row I1 (caps live MFMA results at 32)
        f32x16 d1 = __builtin_amdgcn_mfma_f32_32x32x16_bf16(a1_0, b1, zero, 0, 0, 0);
        f32x16 d2 = __builtin_amdgcn_mfma_f32_32x32x16_bf16(a2_0, b2, zero, 0, 0, 0);
        acc4(partA, d1, d2);
        f32x16 e1 = __builtin_amdgcn_mfma_f32_32x32x16_bf16(a1_1, b1, zero, 0, 0, 0);
        f32x16 e2 = __builtin_amdgcn_mfma_f32_32x32x16_bf16(a2_1, b2, zero, 0, 0, 0);
        acc4(partA, e1, e2);
    }

    if (c == 0) {
        one_tile(corrP, a1_0, a2_0, I0);                    // +T(I0,I0)
        one_tile(corrM, a1_1, a2_1, I0 + 1);                // -T(I1,I0+1)
    } else if (c == 23) {
        int v = I0 + 256; if (v >= nT) v -= nT;
        int y = I0 + 257; if (y >= nT) y -= nT;
        one_tile(corrM, a1_0, a2_0, v);                     // -T(I0,I0+256)
        one_tile(corrP, a1_1, a2_1, y);                     // +T(I1,I0+257)
    }

    float s = 2.0f * (partA.x + partA.y + partA.z + partA.w)
            + (corrP.x + corrP.y + corrP.z + corrP.w)
            - (corrM.x + corrM.y + corrM.z + corrM.w);
#pragma unroll
    for (int off = 32; off > 0; off >>= 1) s += __shfl_down(s, off, 64);
    if (lane == 0) wsum[wv] = s;
    __syncthreads();
    if (tid == 0) {
        float t = wsum[0] + wsum[1] + wsum[2] + wsum[3];
        atomicAdd(out, t);
    }
}

extern "C" void kernel_launch(void* const* d_in, const int* in_sizes, int n_in,
                              void* d_out, int out_size, void* d_ws, size_t ws_size,
                              hipStream_t stream) {
    const float* verts = (const float*)d_in[0];   // (V,3) f32
    const float* tnorm = (const float*)d_in[1];   // (M,3) f32
    const float* tcent = (const float*)d_in[2];   // (M,3) f32
    const int*   sidx  = (const int*)d_in[3];     // (N,3) i32

    int M = in_sizes[1] / 3;
    int N = in_sizes[3] / 3;
    int P = N + M;                                // 16384

    unsigned short* ws = (unsigned short*)d_ws;   // A1|A2|B1|B2 = 4 MB
    float* out = (float*)d_out;

    int bblocks = (P + 255) / 256;
    dc_pack<<<bblocks, 256, 0, stream>>>(verts, tnorm, tcent, sidx, ws, out, N, M);

    // 256 row-pairs x 24 chunks = 6144 waves = 1536 blocks (6/CU, one batch)
    dc_pair_mfma<<<1536, 256, 0, stream>>>(ws, out, P);
}

// Round 12
// 84.769 us; speedup vs baseline: 1.1053x; 1.1053x over previous
//
#include <hip/hip_runtime.h>

typedef short bf16x8 __attribute__((ext_vector_type(8)));
typedef float f32x16 __attribute__((ext_vector_type(16)));

#define GLOAD_LDS16(g, l) __builtin_amdgcn_global_load_lds(                    \
    (const __attribute__((address_space(1))) unsigned int*)(g),                \
    (__attribute__((address_space(3))) unsigned int*)(l), 16, 0, 0)

// round-to-nearest-even fp32 -> bf16 (bits)
static __device__ __forceinline__ unsigned short f2bf(float x) {
    unsigned u = __builtin_bit_cast(unsigned, x);
    unsigned r = (u + 0x7FFFu + ((u >> 16) & 1u)) >> 16;
    return (unsigned short)r;
}
static __device__ __forceinline__ float bf2f(unsigned short h) {
    unsigned u = (unsigned)h << 16;
    return __builtin_bit_cast(float, u);
}

// Workspace (shorts): A1[P*16] | A2[P*16] | B1[P*16] | B2[P*16]

// Kernel 1: per point p build MFMA K-vectors (bf16, hi/lo split) for two grams:
//   gram1: denom = 1 + s_i + s_j - 2<c_i,c_j>;  gram2: dot = <n_i,n_j>
// 32x32x16 fragment layout (verified R5-R11, absmax 0.0): point p -> tile=p>>5,
// m=p&31; k0..7 chunk -> lane m, k8..15 -> lane 32+m.
// Targets carry NEGATED normals (folds e_ss - 2 e_st + e_tt into one sum).
__global__ void dc_pack(const float* __restrict__ verts,
                        const float* __restrict__ tnorm,
                        const float* __restrict__ tcent,
                        const int* __restrict__ idx,
                        unsigned short* __restrict__ ws,
                        float* __restrict__ out,
                        int N, int M) {
    int p = blockIdx.x * blockDim.x + threadIdx.x;
    if (p == 0) out[0] = 0.0f;
    int P = N + M;
    if (p >= P) return;

    float cx, cy, cz, nx, ny, nz;
    if (p < N) {
        int i0 = idx[3 * p + 0], i1 = idx[3 * p + 1], i2 = idx[3 * p + 2];
        float ax = verts[3 * i0], ay = verts[3 * i0 + 1], az = verts[3 * i0 + 2];
        float bx = verts[3 * i1], by = verts[3 * i1 + 1], bz = verts[3 * i1 + 2];
        float qx = verts[3 * i2], qy = verts[3 * i2 + 1], qz = verts[3 * i2 + 2];
        float ux = ax - bx, uy = ay - by, uz = az - bz;
        float vx = qx - bx, vy = qy - by, vz = qz - bz;
        nx = 0.5f * (uy * vz - uz * vy);
        ny = 0.5f * (uz * vx - ux * vz);
        nz = 0.5f * (ux * vy - uy * vx);
        cx = (ax + bx + qx) * (1.0f / 3.0f);
        cy = (ay + by + qy) * (1.0f / 3.0f);
        cz = (az + bz + qz) * (1.0f / 3.0f);
    } else {
        int t = p - N;
        cx = tcent[3 * t]; cy = tcent[3 * t + 1]; cz = tcent[3 * t + 2];
        nx = -tnorm[3 * t]; ny = -tnorm[3 * t + 1]; nz = -tnorm[3 * t + 2];
    }

    unsigned short chx = f2bf(cx), chy = f2bf(cy), chz = f2bf(cz);
    unsigned short clx = f2bf(cx - bf2f(chx));
    unsigned short cly = f2bf(cy - bf2f(chy));
    unsigned short clz = f2bf(cz - bf2f(chz));
    unsigned short nhx = f2bf(nx), nhy = f2bf(ny), nhz = f2bf(nz);
    unsigned short nlx = f2bf(nx - bf2f(nhx));
    unsigned short nly = f2bf(ny - bf2f(nhy));
    unsigned short nlz = f2bf(nz - bf2f(nhz));
    float ex = bf2f(chx) + bf2f(clx);
    float ey = bf2f(chy) + bf2f(cly);
    float ez = bf2f(chz) + bf2f(clz);
    float s = ex * ex + ey * ey + ez * ez;
    unsigned short sh = f2bf(s), sl = f2bf(s - bf2f(sh));
    unsigned short m2hx = f2bf(-2.0f * bf2f(chx)), m2hy = f2bf(-2.0f * bf2f(chy)), m2hz = f2bf(-2.0f * bf2f(chz));
    unsigned short m2lx = f2bf(-2.0f * bf2f(clx)), m2ly = f2bf(-2.0f * bf2f(cly)), m2lz = f2bf(-2.0f * bf2f(clz));
    const unsigned short one = 0x3F80;

    __align__(16) unsigned short A1v[16] = {
        m2hx, m2hy, m2hz,  m2hx, m2hy, m2hz,  m2lx, m2ly, m2lz,
        sh, sl,  one, one,  one,  0, 0 };
    __align__(16) unsigned short B1v[16] = {
        chx, chy, chz,  clx, cly, clz,  chx, chy, chz,
        one, one,  sh, sl,  one,  0, 0 };
    __align__(16) unsigned short A2v[16] = {
        nhx, nhy, nhz,  nhx, nhy, nhz,  nlx, nly, nlz,
        0, 0, 0, 0, 0, 0, 0 };
    __align__(16) unsigned short B2v[16] = {
        nhx, nhy, nhz,  nlx, nly, nlz,  nhx, nhy, nhz,
        0, 0, 0, 0, 0, 0, 0 };

    size_t arr = (size_t)P * 16;
    unsigned short* A1 = ws;
    unsigned short* A2 = ws + arr;
    unsigned short* B1 = ws + 2 * arr;
    unsigned short* B2 = ws + 3 * arr;

    int tile = p >> 5, m = p & 31;
    size_t lo = ((size_t)tile * 64 + m) * 8;       // k0..7 -> lane m
    size_t hi = lo + 32 * 8;                       // k8..15 -> lane 32+m

    *(uint4*)(A1 + lo) = *(const uint4*)&A1v[0];
    *(uint4*)(A1 + hi) = *(const uint4*)&A1v[8];
    *(uint4*)(A2 + lo) = *(const uint4*)&A2v[0];
    *(uint4*)(A2 + hi) = *(const uint4*)&A2v[8];
    *(uint4*)(B1 + lo) = *(const uint4*)&B1v[0];
    *(uint4*)(B1 + hi) = *(const uint4*)&B1v[8];
    *(uint4*)(B2 + lo) = *(const uint4*)&B2v[0];
    *(uint4*)(B2 + hi) = *(const uint4*)&B2v[8];
}

// 4-way batched reciprocal: sum of 4 x/a terms via 1 rcp (trans-pipe 4x cut).
static __device__ __forceinline__ void acc4(float4& part, const f32x16& d1, const f32x16& d2) {
#pragma unroll
    for (int g = 0; g < 4; ++g) {
        const int r = 4 * g;
        float p01 = d1[r] * d1[r + 1];
        float p23 = d1[r + 2] * d1[r + 3];
        float n01 = fmaf(d2[r], d1[r + 1], d2[r + 1] * d1[r]);
        float n23 = fmaf(d2[r + 2], d1[r + 3], d2[r + 3] * d1[r + 2]);
        float t   = p01 * p23;
        float num = fmaf(n01, p23, n23 * p01);
        (&part.x)[g] = fmaf(num, __builtin_amdgcn_rcpf(t), (&part.x)[g]);
    }
}

// Kernel 2: row-paired circular sweep with async LDS staging (m97 structure).
// Rows (I0=2rp, I1=I0+1) share j-window W=[I0+1, I0+256] (mod nT):
//   contrib(rp) = 2*sum_W [T(I0,j)+T(I1,j)]
//               + T(I0,I0) + T(I1,I0+257) - T(I0,I0+256) - T(I1,I0+1)
// Block = (rp, 64-tile chunk). B tiles stream global->LDS via
// global_load_lds (async, no dest-register dependency -- R9/R10's register
// prefetch could not hide L2-under-load latency; this decouples it), 8-tile
// batches, double-buffered (32 KB), one barrier per batch. Each of 4 waves
// stages 2 tiles and processes 2 tiles per batch. 1024 blocks = 4/CU.
__global__ __launch_bounds__(256, 4) void dc_pair_mfma(
    const unsigned short* __restrict__ ws, float* __restrict__ out, int P) {
    __shared__ unsigned short sB[2][8][1024];   // [buf][slot][b1(512)|b2(512)]
    __shared__ float wsum[4];

    const int nT = P >> 5;                     // 512
    size_t arr = (size_t)P * 16;
    const unsigned short* A1 = ws;
    const unsigned short* A2 = ws + arr;
    const unsigned short* B1 = ws + 2 * arr;
    const unsigned short* B2 = ws + 3 * arr;

    int tid = threadIdx.x;
    int lane = tid & 63, wv = tid >> 6;
    int bx = blockIdx.x;                       // 0..1023
    int rp = bx >> 2, c = bx & 3;
    int I0 = 2 * rp, I1 = I0 + 1;

    const size_t lo = (size_t)lane * 8;

    bf16x8 a1_0 = *(const bf16x8*)(A1 + (size_t)I0 * 512 + lo);
    bf16x8 a2_0 = *(const bf16x8*)(A2 + (size_t)I0 * 512 + lo);
    bf16x8 a1_1 = *(const bf16x8*)(A1 + (size_t)I1 * 512 + lo);
    bf16x8 a2_1 = *(const bf16x8*)(A2 + (size_t)I1 * 512 + lo);

    const f32x16 zero = {0.f,0.f,0.f,0.f,0.f,0.f,0.f,0.f,0.f,0.f,0.f,0.f,0.f,0.f,0.f,0.f};
    float4 partA = make_float4(0.f, 0.f, 0.f, 0.f);
    float4 corrP = make_float4(0.f, 0.f, 0.f, 0.f);
    float4 corrM = make_float4(0.f, 0.f, 0.f, 0.f);

    // stage batch b into buffer bf: wave wv stages slots {2wv, 2wv+1}
    auto stage = [&](int b, int bf) {
#pragma unroll
        for (int t = 0; t < 2; ++t) {
            int slot = 2 * wv + t;
            int j = I0 + 1 + 64 * c + 8 * b + slot;    // window offset 1..256
            if (j >= nT) j -= nT;
            const unsigned short* g1 = B1 + (size_t)j * 512 + lo;
            const unsigned short* g2 = B2 + (size_t)j * 512 + lo;
            GLOAD_LDS16(g1, &sB[bf][slot][0]);         // lane -> base + lane*16B
            GLOAD_LDS16(g2, &sB[bf][slot][512]);
        }
    };
    auto process_slot = [&](int bf, int s) {
        const bf16x8 b1 = *(const bf16x8*)&sB[bf][s][lane * 8];
        const bf16x8 b2 = *(const bf16x8*)&sB[bf][s][512 + lane * 8];
        f32x16 d1 = __builtin_amdgcn_mfma_f32_32x32x16_bf16(a1_0, b1, zero, 0, 0, 0);
        f32x16 d2 = __builtin_amdgcn_mfma_f32_32x32x16_bf16(a2_0, b2, zero, 0, 0, 0);
        acc4(partA, d1, d2);
        f32x16 e1 = __builtin_amdgcn_mfma_f32_32x32x16_bf16(a1_1, b1, zero, 0, 0, 0);
        f32x16 e2 = __builtin_amdgcn_mfma_f32_32x32x16_bf16(a2_1, b2, zero, 0, 0, 0);
        acc4(partA, e1, e2);
    };
    auto one_tile = [&](float4& part, const bf16x8& x1, const bf16x8& x2, int jm) {
        const bf16x8 b1 = *(const bf16x8*)(B1 + (size_t)jm * 512 + lo);
        const bf16x8 b2 = *(const bf16x8*)(B2 + (size_t)jm * 512 + lo);
        f32x16 d1 = __builtin_amdgcn_mfma_f32_32x32x16_bf16(x1, b1, zero, 0, 0, 0);
        f32x16 d2 = __builtin_amdgcn_mfma_f32_32x32x16_bf16(x2, b2, zero, 0, 0, 0);
        acc4(part, d1, d2);
    };

    stage(0, 0);
    __syncthreads();                // drains vmcnt -> buf0 ready
#pragma unroll 1
    for (int b = 0; b < 8; ++b) {
        int bf = b & 1;
        if (b < 7) stage(b + 1, bf ^ 1);   // async, consumed after barrier
        process_slot(bf, wv);
        process_slot(bf, wv + 4);
        __syncthreads();            // all reads of bf done; b+1 staged
    }

    // corrections: wave 0 of edge chunks, direct global loads
    if (wv == 0) {
        if (c == 0) {
            one_tile(corrP, a1_0, a2_0, I0);                // +T(I0,I0)
            one_tile(corrM, a1_1, a2_1, I0 + 1);            // -T(I1,I0+1)
        } else if (c == 3) {
            int v = I0 + 256; if (v >= nT) v -= nT;
            int y = I0 + 257; if (y >= nT) y -= nT;
            one_tile(corrM, a1_0, a2_0, v);                 // -T(I0,I0+256)
            one_tile(corrP, a1_1, a2_1, y);                 // +T(I1,I0+257)
        }
    }

    float s = 2.0f * (partA.x + partA.y + partA.z + partA.w)
            + (corrP.x + corrP.y + corrP.z + corrP.w)
            - (corrM.x + corrM.y + corrM.z + corrM.w);
#pragma unroll
    for (int off = 32; off > 0; off >>= 1) s += __shfl_down(s, off, 64);
    if (lane == 0) wsum[wv] = s;
    __syncthreads();
    if (tid == 0) {
        float t = wsum[0] + wsum[1] + wsum[2] + wsum[3];
        atomicAdd(out, t);
    }
}

extern "C" void kernel_launch(void* const* d_in, const int* in_sizes, int n_in,
                              void* d_out, int out_size, void* d_ws, size_t ws_size,
                              hipStream_t stream) {
    const float* verts = (const float*)d_in[0];   // (V,3) f32
    const float* tnorm = (const float*)d_in[1];   // (M,3) f32
    const float* tcent = (const float*)d_in[2];   // (M,3) f32
    const int*   sidx  = (const int*)d_in[3];     // (N,3) i32

    int M = in_sizes[1] / 3;
    int N = in_sizes[3] / 3;
    int P = N + M;                                // 16384

    unsigned short* ws = (unsigned short*)d_ws;   // A1|A2|B1|B2 = 4 MB
    float* out = (float*)d_out;

    int bblocks = (P + 255) / 256;
    dc_pack<<<bblocks, 256, 0, stream>>>(verts, tnorm, tcent, sidx, ws, out, N, M);

    // 256 row-pairs x 4 chunks = 1024 blocks (4/CU, one uniform batch)
    dc_pair_mfma<<<1024, 256, 0, stream>>>(ws, out, P);
}